// Round 3
// baseline (290.252 us; speedup 1.0000x reference)
//
#include <hip/hip_runtime.h>
#include <hip/hip_bf16.h>

// MoE forward: T=4096, H=1024, FFN=4096, E=8, top-2, capacity=1024.
// bf16 grouped GEMMs: 256^2 tile, BK=64, 8 waves (512 thr), 128 KiB LDS,
// 4 phases per K-tile, FULL-TILE 2-deep prefetch: all 8 gld_lds for tile
// t+2 issue at tile t phase 3 (after buf c fully consumed); vmcnt(8) once
// per tile drains exactly tile t's stages. XCD-aware bijective block
// swizzle groups each expert's blocks on one XCD so the 4-way A/B panel
// sharing hits that XCD's L2 (per K-step live slices ~512KB << 4MiB).
//
// ws layout (~136.1 MiB):
//   [0, 64MiB)    hbuf  bf16 [8][1024][4096]
//   +67108864     te    int[8192]
//   +67141632     ew    float[8192]
//   +67174400     perm  int[8192]   (perm[e*1024+c] = slot p, or -1)
//   +67239936     wt    bf16 64MiB  (w1t [e][f][h], later w2t [e][h][f])
//   +134348800    xb    bf16 [4096][1024] (8 MiB)

#define T_TOK 4096
#define HS 1024
#define FFN 4096
#define NE 8
#define CAP 1024
#define TKS 8192

#define WS_TE   67108864
#define WS_EW   67141632
#define WS_PERM 67174400
#define WS_WT   67239936
#define WS_XB   134348800

typedef float f4 __attribute__((ext_vector_type(4)));
typedef __bf16 bf16x8 __attribute__((ext_vector_type(8)));
typedef float f32x4 __attribute__((ext_vector_type(4)));

__device__ __forceinline__ void gld_lds16(const void* g, void* l) {
    __builtin_amdgcn_global_load_lds(
        (const __attribute__((address_space(1))) unsigned int*)g,
        (__attribute__((address_space(3))) unsigned int*)l, 16, 0, 0);
}

// ---------------- init: zero out + copy bias ----------------
__global__ void init_out_kernel(float* __restrict__ out, const float* __restrict__ bias) {
    int i = blockIdx.x * 256 + threadIdx.x;
    const int TH = T_TOK * HS;
    if (i < TH) out[i] = 0.0f;
    else if (i < TH + HS) out[i] = bias[i - TH];
}

// ---------------- router: softmax(x@rw) top-2, fused x->bf16 ----------------
__global__ __launch_bounds__(256) void router_kernel(const float* __restrict__ x,
                                                     const float* __restrict__ rw,
                                                     int* __restrict__ te,
                                                     float* __restrict__ ew,
                                                     __bf16* __restrict__ xb) {
    __shared__ float rwt[NE * HS];
    int tid = threadIdx.x;
    for (int i = tid; i < NE * HS; i += 256) {
        int h = i >> 3, e = i & 7;
        rwt[e * HS + h] = rw[i];
    }
    __syncthreads();
    int wave = tid >> 6, lane = tid & 63;
    int t = blockIdx.x * 4 + wave;
    const float* xr = x + (size_t)t * HS;
    float s[NE];
    float xv[16];
#pragma unroll
    for (int e = 0; e < NE; ++e) s[e] = 0.0f;
#pragma unroll
    for (int j = 0; j < 16; ++j) {
        int h = lane + j * 64;
        xv[j] = xr[h];
#pragma unroll
        for (int e = 0; e < NE; ++e) s[e] += xv[j] * rwt[e * HS + h];
    }
#pragma unroll
    for (int j = 0; j < 16; ++j)
        xb[(size_t)t * HS + lane + j * 64] = (__bf16)xv[j];
#pragma unroll
    for (int e = 0; e < NE; ++e) {
#pragma unroll
        for (int off = 1; off < 64; off <<= 1) s[e] += __shfl_xor(s[e], off, 64);
    }
    float m = s[0];
#pragma unroll
    for (int e = 1; e < NE; ++e) m = fmaxf(m, s[e]);
    float psum = 0.0f;
#pragma unroll
    for (int e = 0; e < NE; ++e) psum += __expf(s[e] - m);
    int e0 = 0; float v0 = s[0];
#pragma unroll
    for (int e = 1; e < NE; ++e) { if (s[e] > v0) { v0 = s[e]; e0 = e; } }
    int e1 = -1; float v1 = -1e30f;
#pragma unroll
    for (int e = 0; e < NE; ++e) { if (e != e0 && s[e] > v1) { v1 = s[e]; e1 = e; } }
    if (lane == 0) {
        float inv = 1.0f / psum;
        te[2 * t]     = e0;
        te[2 * t + 1] = e1;
        ew[2 * t]     = __expf(v0 - m) * inv;
        ew[2 * t + 1] = __expf(v1 - m) * inv;
    }
}

// ---------------- stable counting sort by expert ----------------
__global__ __launch_bounds__(256) void sort_kernel(const int* __restrict__ te,
                                                   int* __restrict__ perm) {
    __shared__ int hist[256 * NE];
    int tid = threadIdx.x;
#pragma unroll
    for (int e = 0; e < NE; ++e) hist[tid * NE + e] = 0;
    for (int i = tid; i < TKS; i += 256) perm[i] = -1;
    __syncthreads();
    for (int j = 0; j < 32; ++j) {
        int p = tid * 32 + j;
        hist[tid * NE + te[p]]++;
    }
    __syncthreads();
    if (tid < NE) {
        int run = 0;
        for (int i = 0; i < 256; ++i) {
            int v = hist[i * NE + tid];
            hist[i * NE + tid] = run;
            run += v;
        }
    }
    __syncthreads();
    for (int j = 0; j < 32; ++j) {
        int p = tid * 32 + j;
        int e = te[p];
        int c = hist[tid * NE + e]++;
        if (c < CAP) perm[e * CAP + c] = p;
    }
}

// ---------------- [E][K][N] fp32 -> [E][N][K] bf16 transpose ----------------
__global__ __launch_bounds__(256) void conv_wt_kernel(const float* __restrict__ w,
                                                      __bf16* __restrict__ wt,
                                                      int K, int N) {
    __shared__ __bf16 t[64][72];
    const int e = blockIdx.z;
    const int kb = blockIdx.y * 64, nb = blockIdx.x * 64;
    const int tid = threadIdx.x;
    const float* src = w + ((size_t)e * K + kb) * N + nb;
    {
        const int kk = tid >> 4, nc = (tid & 15) * 4;
#pragma unroll
        for (int i = 0; i < 4; ++i) {
            int k = kk + 16 * i;
            f4 v = *(const f4*)(src + (size_t)k * N + nc);
            t[nc + 0][k] = (__bf16)v[0];
            t[nc + 1][k] = (__bf16)v[1];
            t[nc + 2][k] = (__bf16)v[2];
            t[nc + 3][k] = (__bf16)v[3];
        }
    }
    __syncthreads();
    __bf16* dst = wt + ((size_t)e * N + nb) * K + kb;
    const int nn = tid >> 3, ch = (tid & 7) * 8;
#pragma unroll
    for (int i = 0; i < 2; ++i) {
        int n = nn + 32 * i;
        bf16x8 v = *(const bf16x8*)(&t[n][ch]);
        *(bf16x8*)(dst + (size_t)n * K + ch) = v;
    }
}

// ---------------- 256^2 pipelined GEMM machinery ----------------
// LDS rows are 128B (64 bf16): granule g in 0..7 of row r holds global
// granule g ^ (r&7). One gld_lds covers 8 rows; lane's row = base +
// (lane>>3), source granule = (lane&7) ^ (lane>>3).
// A half-tile = 128 rows: 8 waves x 2 ops (wave w rows h*128+w*16+{0,8}+srl).

#define PBAR() do {                                                         \
    asm volatile("" ::: "memory");                                          \
    __builtin_amdgcn_s_barrier();                                           \
    asm volatile("" ::: "memory");                                          \
} while (0)

#define WAITV(N_) asm volatile("s_waitcnt vmcnt(" #N_ ")" ::: "memory")

#define STAGE_A(cb_, h_, koff_) do {                                        \
    gld_lds16(aptr[(h_)*2 + 0] + (koff_), &As[cb_][(h_)*128 + w*16 + 0][0]);\
    gld_lds16(aptr[(h_)*2 + 1] + (koff_), &As[cb_][(h_)*128 + w*16 + 8][0]);\
} while (0)

#define STAGE_B(cb_, h_, koff_) do {                                        \
    gld_lds16(bptr[(h_)*2 + 0] + (koff_), &Bs[cb_][(h_)*128 + w*16 + 0][0]);\
    gld_lds16(bptr[(h_)*2 + 1] + (koff_), &Bs[cb_][(h_)*128 + w*16 + 8][0]);\
} while (0)

#define STAGE_TILE(cb_, koff_) do {                                         \
    STAGE_A(cb_, 0, koff_); STAGE_A(cb_, 1, koff_);                         \
    STAGE_B(cb_, 0, koff_); STAGE_B(cb_, 1, koff_);                         \
} while (0)

#define RD_A4(MB_) do {                                                     \
    _Pragma("unroll")                                                       \
    for (int mi = 0; mi < 4; ++mi)                                          \
        _Pragma("unroll")                                                   \
        for (int kk = 0; kk < 2; ++kk)                                      \
            a[mi][kk] = *(const bf16x8*)&As[c][wr*128 + ((MB_)+mi)*16 + l15]\
                            [((kk*4 + (lane>>4)) ^ (lane&7)) * 8];          \
} while (0)

#define RD_B2(NB_) do {                                                     \
    _Pragma("unroll")                                                       \
    for (int ni = 0; ni < 2; ++ni)                                          \
        _Pragma("unroll")                                                   \
        for (int kk = 0; kk < 2; ++kk)                                      \
            b[(NB_)+ni][kk] = *(const bf16x8*)&Bs[c][wc*64 + ((NB_)+ni)*16 + l15]\
                            [((kk*4 + (lane>>4)) ^ (lane&7)) * 8];          \
} while (0)

#define MFMA16(MB_, NB_) do {                                               \
    __builtin_amdgcn_s_setprio(1);                                          \
    _Pragma("unroll")                                                       \
    for (int mi = 0; mi < 4; ++mi)                                          \
        _Pragma("unroll")                                                   \
        for (int ni = 0; ni < 2; ++ni)                                      \
            _Pragma("unroll")                                               \
            for (int kk = 0; kk < 2; ++kk)                                  \
                acc[(MB_)+mi][(NB_)+ni] = __builtin_amdgcn_mfma_f32_16x16x32_bf16(\
                    a[mi][kk], b[(NB_)+ni][kk], acc[(MB_)+mi][(NB_)+ni], 0, 0, 0);\
    __builtin_amdgcn_s_setprio(0);                                          \
} while (0)

// Pipelined K-loop, 2-deep full-tile prefetch.
//   prologue: stage tile0 -> buf0, tile1 -> buf1 (16 ops/wave outstanding).
//   tile t: WAITV(8) drains tile t's 8 stages (keeps t+1's); the loop-top
//   barrier then guarantees ALL waves' stages for t landed. Reads of buf c
//   are consumed by each wave's own MFMA before the p2-end barrier, so the
//   p3 stages into buf c (for tile t+2) are race-free.
#define KLOOP(NT_)                                                          \
    STAGE_TILE(0, 0);                                                       \
    STAGE_TILE(1, 64);                                                      \
    for (int t = 0; t < (NT_); ++t) {                                       \
        const int c = t & 1;                                                \
        if (t == (NT_) - 1) WAITV(0); else WAITV(8);                        \
        PBAR();                                                             \
        /* phase 0 */                                                       \
        RD_A4(0); RD_B2(0);                                                 \
        PBAR();                                                             \
        MFMA16(0, 0);                                                       \
        PBAR();                                                             \
        /* phase 1 */                                                       \
        RD_B2(2);                                                           \
        PBAR();                                                             \
        MFMA16(0, 2);                                                       \
        PBAR();                                                             \
        /* phase 2 */                                                       \
        RD_A4(4);                                                           \
        PBAR();                                                             \
        MFMA16(4, 2);                                                       \
        PBAR();                                                             \
        /* phase 3: stage ALL of tile t+2 into buf c, then compute */       \
        if (t + 2 < (NT_)) STAGE_TILE(c, (t + 2) * 64);                     \
        __builtin_amdgcn_sched_barrier(0);                                  \
        MFMA16(4, 0);                                                       \
    }

// ---------------- GEMM1: h = gelu(gather(xb) @ w1t^T) ----------------
// Logical grid 16 x 4 x 8 (nblk, mblk, e); XCD k <- expert k (64 blocks).
__global__ __launch_bounds__(512, 2) void gemm1_kernel(const __bf16* __restrict__ xb,
                                                       const __bf16* __restrict__ w1t,
                                                       const int* __restrict__ perm,
                                                       __bf16* __restrict__ hbuf) {
    __shared__ __bf16 As[2][256][64];
    __shared__ __bf16 Bs[2][256][64];
    const int hw = blockIdx.x + 16 * blockIdx.y + 64 * blockIdx.z;
    const int logical = (hw & 7) * 64 + (hw >> 3);   // bijective, nwg=512
    const int nblk = logical & 15;
    const int mblk = (logical >> 4) & 3;
    const int e    = logical >> 6;
    const int tid = threadIdx.x, lane = tid & 63, w = tid >> 6;  // w in 0..7
    const int wr = w >> 2, wc = w & 3;
    const int l15 = lane & 15;
    const int srl = lane >> 3;
    const int gsrc = (lane & 7) ^ srl;

    const __bf16* aptr[4];
    const __bf16* bptr[4];
#pragma unroll
    for (int h = 0; h < 2; ++h) {
#pragma unroll
        for (int o = 0; o < 2; ++o) {
            int r = h * 128 + w * 16 + o * 8 + srl;
            int p = perm[e * CAP + mblk * 256 + r];
            int tok = (p < 0) ? 0 : (p >> 1);
            aptr[h * 2 + o] = xb + (size_t)tok * HS + gsrc * 8;
            int brow = nblk * 256 + r;
            bptr[h * 2 + o] = w1t + ((size_t)e * FFN + brow) * HS + gsrc * 8;
        }
    }

    f32x4 acc[8][4];
#pragma unroll
    for (int mi = 0; mi < 8; ++mi)
#pragma unroll
        for (int ni = 0; ni < 4; ++ni) acc[mi][ni] = (f32x4)0.0f;
    bf16x8 a[4][2], b[4][2];

    KLOOP(HS / 64)  // 16 K-tiles

    const int mbase = mblk * 256 + wr * 128;
    const int nbase = nblk * 256 + wc * 64;
#pragma unroll
    for (int mi = 0; mi < 8; ++mi) {
#pragma unroll
        for (int ni = 0; ni < 4; ++ni) {
#pragma unroll
            for (int reg = 0; reg < 4; ++reg) {
                int mrow = mbase + mi * 16 + (lane >> 4) * 4 + reg;
                int ncol = nbase + ni * 16 + l15;
                float z = acc[mi][ni][reg];
                // gelu(z) = 0.5 z (1+tanh(u)) == z * sigmoid(2u)
                float z2 = z * z;
                float y = z * (1.5957691216057308f + 0.07135481627f * z2);
                float ex = __expf(-y);
                float gv = z * __builtin_amdgcn_rcpf(1.0f + ex);
                hbuf[(size_t)(e * CAP + mrow) * FFN + ncol] = (__bf16)gv;
            }
        }
    }
}

// ---------------- GEMM2: y = h @ w2t^T, scatter += w*y; 2-way K-split ----------------
// Logical grid 4 x 4 x 16 (nblk, mblk, z=(e,half)); XCD k <- expert k (32 blocks).
__global__ __launch_bounds__(512, 2) void gemm2_kernel(const __bf16* __restrict__ hbuf,
                                                       const __bf16* __restrict__ w2t,
                                                       const int* __restrict__ perm,
                                                       const float* __restrict__ ew,
                                                       float* __restrict__ out) {
    __shared__ __bf16 As[2][256][64];
    __shared__ __bf16 Bs[2][256][64];
    const int hw = blockIdx.x + 4 * blockIdx.y + 16 * blockIdx.z;
    const int logical = (hw & 7) * 32 + (hw >> 3);   // bijective, nwg=256
    const int nblk = logical & 3;
    const int mblk = (logical >> 2) & 3;
    const int zz   = logical >> 4;                   // 0..15
    const int e    = zz >> 1, half = zz & 1;
    const int tid = threadIdx.x, lane = tid & 63, w = tid >> 6;
    const int wr = w >> 2, wc = w & 3;
    const int l15 = lane & 15;
    const int srl = lane >> 3;
    const int gsrc = (lane & 7) ^ srl;
    const size_t kbase = (size_t)half * 2048;

    const __bf16* aptr[4];
    const __bf16* bptr[4];
#pragma unroll
    for (int h = 0; h < 2; ++h) {
#pragma unroll
        for (int o = 0; o < 2; ++o) {
            int r = h * 128 + w * 16 + o * 8 + srl;
            aptr[h * 2 + o] = hbuf + ((size_t)(e * CAP + mblk * 256 + r)) * FFN
                              + kbase + gsrc * 8;
            int brow = nblk * 256 + r;
            bptr[h * 2 + o] = w2t + ((size_t)e * HS + brow) * FFN
                              + kbase + gsrc * 8;
        }
    }

    f32x4 acc[8][4];
#pragma unroll
    for (int mi = 0; mi < 8; ++mi)
#pragma unroll
        for (int ni = 0; ni < 4; ++ni) acc[mi][ni] = (f32x4)0.0f;
    bf16x8 a[4][2], b[4][2];

    KLOOP(2048 / 64)  // 32 K-tiles

    // reuse LDS for perm/weights of this block's 256 rows
    __syncthreads();
    int* sperm = (int*)&As[0][0][0];
    float* swt = (float*)(sperm + 256);
    if (tid < 256) {
        int p = perm[e * CAP + mblk * 256 + tid];
        sperm[tid] = p;
        swt[tid] = (p >= 0) ? ew[p] : 0.0f;
    }
    __syncthreads();

    const int nbase = nblk * 256 + wc * 64;
#pragma unroll
    for (int mi = 0; mi < 8; ++mi) {
#pragma unroll
        for (int reg = 0; reg < 4; ++reg) {
            int mloc = wr * 128 + mi * 16 + (lane >> 4) * 4 + reg;
            int p = sperm[mloc];
            if (p >= 0) {
                int tok = p >> 1;
                float wgt = swt[mloc];
#pragma unroll
                for (int ni = 0; ni < 4; ++ni) {
                    int n = nbase + ni * 16 + l15;
                    atomicAdd(&out[(size_t)tok * HS + n], wgt * acc[mi][ni][reg]);
                }
            }
        }
    }
}

extern "C" void kernel_launch(void* const* d_in, const int* in_sizes, int n_in,
                              void* d_out, int out_size, void* d_ws, size_t ws_size,
                              hipStream_t stream) {
    const float* x    = (const float*)d_in[0];
    const float* rw   = (const float*)d_in[1];
    const float* w1   = (const float*)d_in[2];
    const float* w2   = (const float*)d_in[3];
    const float* bias = (const float*)d_in[4];
    float* out = (float*)d_out;
    char* ws = (char*)d_ws;

    __bf16* hbuf = (__bf16*)ws;
    int*    te   = (int*)(ws + WS_TE);
    float*  ew   = (float*)(ws + WS_EW);
    int*    perm = (int*)(ws + WS_PERM);
    __bf16* wt   = (__bf16*)(ws + WS_WT);
    __bf16* xb   = (__bf16*)(ws + WS_XB);

    hipLaunchKernelGGL(init_out_kernel, dim3((T_TOK * HS + HS + 255) / 256), dim3(256),
                       0, stream, out, bias);
    hipLaunchKernelGGL(router_kernel, dim3(T_TOK / 4), dim3(256), 0, stream,
                       x, rw, te, ew, xb);
    hipLaunchKernelGGL(sort_kernel, dim3(1), dim3(256), 0, stream, te, perm);
    hipLaunchKernelGGL(conv_wt_kernel, dim3(FFN / 64, HS / 64, NE), dim3(256),
                       0, stream, w1, wt, HS, FFN);
    hipLaunchKernelGGL(gemm1_kernel, dim3(FFN / 256, CAP / 256, NE), dim3(512),
                       0, stream, xb, wt, perm, hbuf);
    hipLaunchKernelGGL(conv_wt_kernel, dim3(HS / 64, FFN / 64, NE), dim3(256),
                       0, stream, w2, wt, FFN, HS);
    hipLaunchKernelGGL(gemm2_kernel, dim3(HS / 256, CAP / 256, NE * 2), dim3(512),
                       0, stream, hbuf, wt, perm, ew, out);
}

// Round 4
// 276.263 us; speedup vs baseline: 1.0506x; 1.0506x over previous
//
#include <hip/hip_runtime.h>
#include <hip/hip_bf16.h>

// MoE forward: T=4096, H=1024, FFN=4096, E=8, top-2, capacity=1024.
// bf16 grouped GEMMs: 256^2 tile, BK=64, 8 waves, 128 KiB LDS.
// K-loop: 4 phases/K-tile, inline-asm ds_read_b128 (invisible to the
// waitcnt pass so it cannot re-insert vmcnt(0) against global_load_lds),
// explicit lgkmcnt(0)+sched_barrier before each MFMA cluster (rule #18),
// counted vmcnt(6) once per tile (vmcnt(0) only at last tile), stage
// schedule gives every half-tile >=4 phases of latency cover:
//   tile t issues: p0: T(t+1).A1 -> buf o ; p2: T(t+2).B0 -> buf c ;
//                  p3: T(t+2).B1, T(t+2).A0 -> buf c        (8 ops/tile)
// Ledger at tile-t top: outstanding = T(t).{B0,B1,A0} (from t-2) +
//   T(t).A1 + T(t+1).{B0,B1,A0} (from t-1) = 14 ops; vmcnt(6) keeps the
//   newest 6 = T(t+1).{B0,B1,A0}, drains all of T(t). Same-phase
//   stage/read regions disjoint; reads lgkm-drained before each phase's
//   trailing barrier so next-phase overwrites are race-free.
// XOR granule swizzle (pre-swizzled per-lane global source, swizzled
// ds_read position); XCD-aware bijective block swizzle (expert -> XCD).
//
// ws layout (~136.1 MiB):
//   [0, 64MiB)    hbuf  bf16 [8][1024][4096]
//   +67108864     te    int[8192]
//   +67141632     ew    float[8192]
//   +67174400     perm  int[8192]   (perm[e*1024+c] = slot p, or -1)
//   +67239936     wt    bf16 64MiB  (w1t [e][f][h], later w2t [e][h][f])
//   +134348800    xb    bf16 [4096][1024] (8 MiB)

#define T_TOK 4096
#define HS 1024
#define FFN 4096
#define NE 8
#define CAP 1024
#define TKS 8192

#define WS_TE   67108864
#define WS_EW   67141632
#define WS_PERM 67174400
#define WS_WT   67239936
#define WS_XB   134348800

typedef float f4 __attribute__((ext_vector_type(4)));
typedef __bf16 bf16x8 __attribute__((ext_vector_type(8)));
typedef float f32x4 __attribute__((ext_vector_type(4)));

__device__ __forceinline__ void gld_lds16(const void* g, void* l) {
    __builtin_amdgcn_global_load_lds(
        (const __attribute__((address_space(1))) unsigned int*)g,
        (__attribute__((address_space(3))) unsigned int*)l, 16, 0, 0);
}

// inline-asm LDS read: untracked by SIInsertWaitcnts, so the compiler
// cannot tie it to outstanding global_load_lds and force vmcnt(0).
__device__ __forceinline__ bf16x8 ds_read16(const void* p) {
    bf16x8 r;
    unsigned off = (unsigned)(size_t)(const __attribute__((address_space(3))) char*)p;
    asm volatile("ds_read_b128 %0, %1" : "=&v"(r) : "v"(off));
    return r;
}

// ---------------- init: zero out + copy bias ----------------
__global__ void init_out_kernel(float* __restrict__ out, const float* __restrict__ bias) {
    int i = blockIdx.x * 256 + threadIdx.x;
    const int TH = T_TOK * HS;
    if (i < TH) out[i] = 0.0f;
    else if (i < TH + HS) out[i] = bias[i - TH];
}

// ---------------- router: softmax(x@rw) top-2, fused x->bf16 ----------------
__global__ __launch_bounds__(256) void router_kernel(const float* __restrict__ x,
                                                     const float* __restrict__ rw,
                                                     int* __restrict__ te,
                                                     float* __restrict__ ew,
                                                     __bf16* __restrict__ xb) {
    __shared__ float rwt[NE * HS];
    int tid = threadIdx.x;
    for (int i = tid; i < NE * HS; i += 256) {
        int h = i >> 3, e = i & 7;
        rwt[e * HS + h] = rw[i];
    }
    __syncthreads();
    int wave = tid >> 6, lane = tid & 63;
    int t = blockIdx.x * 4 + wave;
    const float* xr = x + (size_t)t * HS;
    float s[NE];
    float xv[16];
#pragma unroll
    for (int e = 0; e < NE; ++e) s[e] = 0.0f;
#pragma unroll
    for (int j = 0; j < 16; ++j) {
        int h = lane + j * 64;
        xv[j] = xr[h];
#pragma unroll
        for (int e = 0; e < NE; ++e) s[e] += xv[j] * rwt[e * HS + h];
    }
#pragma unroll
    for (int j = 0; j < 16; ++j)
        xb[(size_t)t * HS + lane + j * 64] = (__bf16)xv[j];
#pragma unroll
    for (int e = 0; e < NE; ++e) {
#pragma unroll
        for (int off = 1; off < 64; off <<= 1) s[e] += __shfl_xor(s[e], off, 64);
    }
    float m = s[0];
#pragma unroll
    for (int e = 1; e < NE; ++e) m = fmaxf(m, s[e]);
    float psum = 0.0f;
#pragma unroll
    for (int e = 0; e < NE; ++e) psum += __expf(s[e] - m);
    int e0 = 0; float v0 = s[0];
#pragma unroll
    for (int e = 1; e < NE; ++e) { if (s[e] > v0) { v0 = s[e]; e0 = e; } }
    int e1 = -1; float v1 = -1e30f;
#pragma unroll
    for (int e = 0; e < NE; ++e) { if (e != e0 && s[e] > v1) { v1 = s[e]; e1 = e; } }
    if (lane == 0) {
        float inv = 1.0f / psum;
        te[2 * t]     = e0;
        te[2 * t + 1] = e1;
        ew[2 * t]     = __expf(v0 - m) * inv;
        ew[2 * t + 1] = __expf(v1 - m) * inv;
    }
}

// ---------------- stable counting sort by expert ----------------
__global__ __launch_bounds__(256) void sort_kernel(const int* __restrict__ te,
                                                   int* __restrict__ perm) {
    __shared__ int hist[256 * NE];
    int tid = threadIdx.x;
#pragma unroll
    for (int e = 0; e < NE; ++e) hist[tid * NE + e] = 0;
    for (int i = tid; i < TKS; i += 256) perm[i] = -1;
    __syncthreads();
    for (int j = 0; j < 32; ++j) {
        int p = tid * 32 + j;
        hist[tid * NE + te[p]]++;
    }
    __syncthreads();
    if (tid < NE) {
        int run = 0;
        for (int i = 0; i < 256; ++i) {
            int v = hist[i * NE + tid];
            hist[i * NE + tid] = run;
            run += v;
        }
    }
    __syncthreads();
    for (int j = 0; j < 32; ++j) {
        int p = tid * 32 + j;
        int e = te[p];
        int c = hist[tid * NE + e]++;
        if (c < CAP) perm[e * CAP + c] = p;
    }
}

// ---------------- [E][K][N] fp32 -> [E][N][K] bf16 transpose ----------------
__global__ __launch_bounds__(256) void conv_wt_kernel(const float* __restrict__ w,
                                                      __bf16* __restrict__ wt,
                                                      int K, int N) {
    __shared__ __bf16 t[64][72];
    const int e = blockIdx.z;
    const int kb = blockIdx.y * 64, nb = blockIdx.x * 64;
    const int tid = threadIdx.x;
    const float* src = w + ((size_t)e * K + kb) * N + nb;
    {
        const int kk = tid >> 4, nc = (tid & 15) * 4;
#pragma unroll
        for (int i = 0; i < 4; ++i) {
            int k = kk + 16 * i;
            f4 v = *(const f4*)(src + (size_t)k * N + nc);
            t[nc + 0][k] = (__bf16)v[0];
            t[nc + 1][k] = (__bf16)v[1];
            t[nc + 2][k] = (__bf16)v[2];
            t[nc + 3][k] = (__bf16)v[3];
        }
    }
    __syncthreads();
    __bf16* dst = wt + ((size_t)e * N + nb) * K + kb;
    const int nn = tid >> 3, ch = (tid & 7) * 8;
#pragma unroll
    for (int i = 0; i < 2; ++i) {
        int n = nn + 32 * i;
        bf16x8 v = *(const bf16x8*)(&t[n][ch]);
        *(bf16x8*)(dst + (size_t)n * K + ch) = v;
    }
}

// ---------------- 256^2 pipelined GEMM machinery ----------------
// LDS rows are 128B (64 bf16): granule g in 0..7 of row r holds global
// granule g ^ (r&7). One gld_lds covers 8 rows; lane's row = base +
// (lane>>3), source granule = (lane&7) ^ (lane>>3).
// Half-tile = 128 rows: 8 waves x 2 ops (wave w rows h*128+w*16+{0,8}+srl).

#define PBAR() do {                                                         \
    asm volatile("" ::: "memory");                                          \
    __builtin_amdgcn_s_barrier();                                           \
    asm volatile("" ::: "memory");                                          \
} while (0)

#define WAITV(N_) asm volatile("s_waitcnt vmcnt(" #N_ ")" ::: "memory")

#define LGKM0() do {                                                        \
    asm volatile("s_waitcnt lgkmcnt(0)" ::: "memory");                      \
    __builtin_amdgcn_sched_barrier(0);                                      \
} while (0)

#define STAGE_A(cb_, h_, koff_) do {                                        \
    gld_lds16(aptr[(h_)*2 + 0] + (koff_), &As[cb_][(h_)*128 + w*16 + 0][0]);\
    gld_lds16(aptr[(h_)*2 + 1] + (koff_), &As[cb_][(h_)*128 + w*16 + 8][0]);\
} while (0)

#define STAGE_B(cb_, h_, koff_) do {                                        \
    gld_lds16(bptr[(h_)*2 + 0] + (koff_), &Bs[cb_][(h_)*128 + w*16 + 0][0]);\
    gld_lds16(bptr[(h_)*2 + 1] + (koff_), &Bs[cb_][(h_)*128 + w*16 + 8][0]);\
} while (0)

#define RD_A4(MB_) do {                                                     \
    _Pragma("unroll")                                                       \
    for (int mi = 0; mi < 4; ++mi)                                          \
        _Pragma("unroll")                                                   \
        for (int kk = 0; kk < 2; ++kk)                                      \
            a[mi][kk] = ds_read16(&As[c][wr*128 + ((MB_)+mi)*16 + l15]      \
                            [(((kk*4 + (lane>>4)) ^ (lane&7)) * 8)]);       \
} while (0)

#define RD_B2(NB_) do {                                                     \
    _Pragma("unroll")                                                       \
    for (int ni = 0; ni < 2; ++ni)                                          \
        _Pragma("unroll")                                                   \
        for (int kk = 0; kk < 2; ++kk)                                      \
            b[(NB_)+ni][kk] = ds_read16(&Bs[c][wc*64 + ((NB_)+ni)*16 + l15] \
                            [(((kk*4 + (lane>>4)) ^ (lane&7)) * 8)]);       \
} while (0)

#define MFMA16(MB_, NB_) do {                                               \
    __builtin_amdgcn_s_setprio(1);                                          \
    _Pragma("unroll")                                                       \
    for (int mi = 0; mi < 4; ++mi)                                          \
        _Pragma("unroll")                                                   \
        for (int ni = 0; ni < 2; ++ni)                                      \
            _Pragma("unroll")                                               \
            for (int kk = 0; kk < 2; ++kk)                                  \
                acc[(MB_)+mi][(NB_)+ni] = __builtin_amdgcn_mfma_f32_16x16x32_bf16(\
                    a[mi][kk], b[(NB_)+ni][kk], acc[(MB_)+mi][(NB_)+ni], 0, 0, 0);\
    __builtin_amdgcn_s_setprio(0);                                          \
} while (0)

// Pipelined K-loop. Prologue stages T0 fully + T1.{B0,B1,A0}; the newest 6
// outstanding ops at every tile top are the next tile's {B0,B1,A0}.
#define KLOOP(NT_)                                                          \
    STAGE_B(0, 0, 0); STAGE_B(0, 1, 0);                                     \
    STAGE_A(0, 0, 0); STAGE_A(0, 1, 0);                                     \
    STAGE_B(1, 0, 64); STAGE_B(1, 1, 64);                                   \
    STAGE_A(1, 0, 64);                                                      \
    for (int t = 0; t < (NT_); ++t) {                                       \
        const int c = t & 1, o = c ^ 1;                                     \
        if (t == (NT_) - 1) WAITV(0); else WAITV(6);                        \
        PBAR();                                                             \
        /* p0: read A0-3,B0-1(buf c); stage T(t+1).A1 -> buf o */           \
        RD_A4(0); RD_B2(0);                                                 \
        if (t + 1 < (NT_)) STAGE_A(o, 1, (t + 1) * 64);                     \
        PBAR(); LGKM0();                                                    \
        MFMA16(0, 0);                                                       \
        PBAR();                                                             \
        /* p1: read B2-3(buf c) */                                          \
        RD_B2(2);                                                           \
        PBAR(); LGKM0();                                                    \
        MFMA16(0, 2);                                                       \
        PBAR();                                                             \
        /* p2: read A4-7(buf c); stage T(t+2).B0 -> buf c (B free) */       \
        RD_A4(4);                                                           \
        if (t + 2 < (NT_)) STAGE_B(c, 0, (t + 2) * 64);                     \
        PBAR(); LGKM0();                                                    \
        MFMA16(4, 2);                                                       \
        PBAR();                                                             \
        /* p3: stage T(t+2).B1,A0 -> buf c (A free after p2) */             \
        if (t + 2 < (NT_)) { STAGE_B(c, 1, (t + 2) * 64);                   \
                             STAGE_A(c, 0, (t + 2) * 64); }                 \
        PBAR();                                                             \
        MFMA16(4, 0);                                                       \
        PBAR();                                                             \
    }

// ---------------- GEMM1: h = gelu(gather(xb) @ w1t^T) ----------------
// Logical grid 16 x 4 x 8 (nblk, mblk, e); XCD k <- expert k (64 blocks).
__global__ __launch_bounds__(512, 2) void gemm1_kernel(const __bf16* __restrict__ xb,
                                                       const __bf16* __restrict__ w1t,
                                                       const int* __restrict__ perm,
                                                       __bf16* __restrict__ hbuf) {
    __shared__ __bf16 As[2][256][64];
    __shared__ __bf16 Bs[2][256][64];
    const int hw = blockIdx.x + 16 * blockIdx.y + 64 * blockIdx.z;
    const int logical = (hw & 7) * 64 + (hw >> 3);   // bijective, nwg=512
    const int nblk = logical & 15;
    const int mblk = (logical >> 4) & 3;
    const int e    = logical >> 6;
    const int tid = threadIdx.x, lane = tid & 63, w = tid >> 6;  // w in 0..7
    const int wr = w >> 2, wc = w & 3;
    const int l15 = lane & 15;
    const int srl = lane >> 3;
    const int gsrc = (lane & 7) ^ srl;

    const __bf16* aptr[4];
    const __bf16* bptr[4];
#pragma unroll
    for (int h = 0; h < 2; ++h) {
#pragma unroll
        for (int o2 = 0; o2 < 2; ++o2) {
            int r = h * 128 + w * 16 + o2 * 8 + srl;
            int p = perm[e * CAP + mblk * 256 + r];
            int tok = (p < 0) ? 0 : (p >> 1);
            aptr[h * 2 + o2] = xb + (size_t)tok * HS + gsrc * 8;
            int brow = nblk * 256 + r;
            bptr[h * 2 + o2] = w1t + ((size_t)e * FFN + brow) * HS + gsrc * 8;
        }
    }

    f32x4 acc[8][4];
#pragma unroll
    for (int mi = 0; mi < 8; ++mi)
#pragma unroll
        for (int ni = 0; ni < 4; ++ni) acc[mi][ni] = (f32x4)0.0f;
    bf16x8 a[4][2], b[4][2];

    KLOOP(HS / 64)  // 16 K-tiles

    const int mbase = mblk * 256 + wr * 128;
    const int nbase = nblk * 256 + wc * 64;
#pragma unroll
    for (int mi = 0; mi < 8; ++mi) {
#pragma unroll
        for (int ni = 0; ni < 4; ++ni) {
#pragma unroll
            for (int reg = 0; reg < 4; ++reg) {
                int mrow = mbase + mi * 16 + (lane >> 4) * 4 + reg;
                int ncol = nbase + ni * 16 + l15;
                float z = acc[mi][ni][reg];
                // gelu(z) = 0.5 z (1+tanh(u)) == z * sigmoid(2u)
                float z2 = z * z;
                float y = z * (1.5957691216057308f + 0.07135481627f * z2);
                float ex = __expf(-y);
                float gv = z * __builtin_amdgcn_rcpf(1.0f + ex);
                hbuf[(size_t)(e * CAP + mrow) * FFN + ncol] = (__bf16)gv;
            }
        }
    }
}

// ---------------- GEMM2: y = h @ w2t^T, scatter += w*y; 2-way K-split ----------------
// Logical grid 4 x 4 x 16 (nblk, mblk, z=(e,half)); XCD k <- expert k (32 blocks).
__global__ __launch_bounds__(512, 2) void gemm2_kernel(const __bf16* __restrict__ hbuf,
                                                       const __bf16* __restrict__ w2t,
                                                       const int* __restrict__ perm,
                                                       const float* __restrict__ ew,
                                                       float* __restrict__ out) {
    __shared__ __bf16 As[2][256][64];
    __shared__ __bf16 Bs[2][256][64];
    const int hw = blockIdx.x + 4 * blockIdx.y + 16 * blockIdx.z;
    const int logical = (hw & 7) * 32 + (hw >> 3);   // bijective, nwg=256
    const int nblk = logical & 3;
    const int mblk = (logical >> 2) & 3;
    const int zz   = logical >> 4;                   // 0..15
    const int e    = zz >> 1, half = zz & 1;
    const int tid = threadIdx.x, lane = tid & 63, w = tid >> 6;
    const int wr = w >> 2, wc = w & 3;
    const int l15 = lane & 15;
    const int srl = lane >> 3;
    const int gsrc = (lane & 7) ^ srl;
    const size_t kbase = (size_t)half * 2048;

    const __bf16* aptr[4];
    const __bf16* bptr[4];
#pragma unroll
    for (int h = 0; h < 2; ++h) {
#pragma unroll
        for (int o2 = 0; o2 < 2; ++o2) {
            int r = h * 128 + w * 16 + o2 * 8 + srl;
            aptr[h * 2 + o2] = hbuf + ((size_t)(e * CAP + mblk * 256 + r)) * FFN
                               + kbase + gsrc * 8;
            int brow = nblk * 256 + r;
            bptr[h * 2 + o2] = w2t + ((size_t)e * HS + brow) * FFN
                               + kbase + gsrc * 8;
        }
    }

    f32x4 acc[8][4];
#pragma unroll
    for (int mi = 0; mi < 8; ++mi)
#pragma unroll
        for (int ni = 0; ni < 4; ++ni) acc[mi][ni] = (f32x4)0.0f;
    bf16x8 a[4][2], b[4][2];

    KLOOP(2048 / 64)  // 32 K-tiles

    // reuse LDS for perm/weights of this block's 256 rows
    __syncthreads();
    int* sperm = (int*)&As[0][0][0];
    float* swt = (float*)(sperm + 256);
    if (tid < 256) {
        int p = perm[e * CAP + mblk * 256 + tid];
        sperm[tid] = p;
        swt[tid] = (p >= 0) ? ew[p] : 0.0f;
    }
    __syncthreads();

    const int nbase = nblk * 256 + wc * 64;
#pragma unroll
    for (int mi = 0; mi < 8; ++mi) {
#pragma unroll
        for (int reg = 0; reg < 4; ++reg) {
            int mloc = wr * 128 + mi * 16 + (lane >> 4) * 4 + reg;
            int p = sperm[mloc];
            if (p >= 0) {
                int tok = p >> 1;
                float wgt = swt[mloc];
#pragma unroll
                for (int ni = 0; ni < 4; ++ni) {
                    int n = nbase + ni * 16 + l15;
                    atomicAdd(&out[(size_t)tok * HS + n], wgt * acc[mi][ni][reg]);
                }
            }
        }
    }
}

extern "C" void kernel_launch(void* const* d_in, const int* in_sizes, int n_in,
                              void* d_out, int out_size, void* d_ws, size_t ws_size,
                              hipStream_t stream) {
    const float* x    = (const float*)d_in[0];
    const float* rw   = (const float*)d_in[1];
    const float* w1   = (const float*)d_in[2];
    const float* w2   = (const float*)d_in[3];
    const float* bias = (const float*)d_in[4];
    float* out = (float*)d_out;
    char* ws = (char*)d_ws;

    __bf16* hbuf = (__bf16*)ws;
    int*    te   = (int*)(ws + WS_TE);
    float*  ew   = (float*)(ws + WS_EW);
    int*    perm = (int*)(ws + WS_PERM);
    __bf16* wt   = (__bf16*)(ws + WS_WT);
    __bf16* xb   = (__bf16*)(ws + WS_XB);

    hipLaunchKernelGGL(init_out_kernel, dim3((T_TOK * HS + HS + 255) / 256), dim3(256),
                       0, stream, out, bias);
    hipLaunchKernelGGL(router_kernel, dim3(T_TOK / 4), dim3(256), 0, stream,
                       x, rw, te, ew, xb);
    hipLaunchKernelGGL(sort_kernel, dim3(1), dim3(256), 0, stream, te, perm);
    hipLaunchKernelGGL(conv_wt_kernel, dim3(FFN / 64, HS / 64, NE), dim3(256),
                       0, stream, w1, wt, HS, FFN);
    hipLaunchKernelGGL(gemm1_kernel, dim3(FFN / 256, CAP / 256, NE), dim3(512),
                       0, stream, xb, wt, perm, hbuf);
    hipLaunchKernelGGL(conv_wt_kernel, dim3(HS / 64, FFN / 64, NE), dim3(256),
                       0, stream, w2, wt, FFN, HS);
    hipLaunchKernelGGL(gemm2_kernel, dim3(HS / 256, CAP / 256, NE * 2), dim3(512),
                       0, stream, hbuf, wt, perm, ew, out);
}